// Round 6
// baseline (282.924 us; speedup 1.0000x reference)
//
#include <hip/hip_runtime.h>
#include <math.h>

// Problem constants (B=64, P=2, H=512, W=512)
#define BP 128                  // B*P pairs
#define PLANE 262144            // elems per (b,p) plane
#define CHUNK_FL 8192           // floats per block chunk (32 KB)
#define NBLK 4096               // blocks per tensor (input / target)
#define NPARTN 4096             // partial records per quantity

// ws float layout: [0,4096) sum, [4096,8192) sumx, [8192,12288) sumy,
// [12288,16384) maxval ; ints at float offset [16384,20480) maxidx. 80 KiB.

// R5 lesson: VGPR-destination loads get serialized by the allocator no matter
// what the source/sched_barrier says (VGPR stuck at 32-36 across 5 rounds).
// global_load_lds has NO destination VGPRs -> the wave issues 8 x 1KB DMA
// back-to-back, 8 KB in flight per wave, ~128 KB per CU. The allocator cannot
// touch it. Then reduce out of LDS at ~85 B/cyc/CU.
__device__ __forceinline__ void load_lds16(const float* g, float* l) {
    __builtin_amdgcn_global_load_lds(
        (const __attribute__((address_space(1))) void*)g,
        (__attribute__((address_space(3))) void*)l,
        16, 0, 0);
}

__global__ __launch_bounds__(256, 4) void dsnt_partial(
    const float* __restrict__ inp, const float* __restrict__ tgt,
    float* __restrict__ wsf, int* __restrict__ wsi)
{
    __shared__ float smem[CHUNK_FL];     // 32 KB staging buffer
    __shared__ float rs[4], rsx[4], rsy[4], rmv[4];
    __shared__ int   rmi[4];

    const int tid  = threadIdx.x;        // 0..255 (4 waves)
    const int blk  = blockIdx.x;         // 0..8191
    const int lane = tid & 63, wid = tid >> 6;
    const float inv = 1.0f / 512.0f;

    const bool is_input = (blk < NBLK);
    const int  cidx     = is_input ? blk : (blk - NBLK);   // chunk id 0..4095
    const float* gbase  = (is_input ? inp : tgt) + (size_t)cidx * CHUNK_FL;

    // ---- stage 32 KB global -> LDS: 32 x 1KB DMA, 8 per wave, no VGPR dest ----
    {
        const float* gw = gbase + lane * 4;   // lane's 16 B within each 1 KB row
#pragma unroll
        for (int k = 0; k < 8; ++k) {
            const int i = wid * 8 + k;        // 1 KB row index 0..31
            load_lds16(gw + i * 256, smem + i * 256);  // lds dest wave-uniform
        }
    }
    asm volatile("s_waitcnt vmcnt(0)" ::: "memory");
    __syncthreads();

    const float4* l4 = (const float4*)smem;
    const int cb = (cidx & 31) * CHUNK_FL;   // chunk base elem within its plane

    if (is_input) {
        // ---- softmax partials from LDS ----
        float s = 0.0f, sx = 0.0f, sy = 0.0f;
#pragma unroll
        for (int k = 0; k < 8; ++k) {
            const float4 v = l4[tid + k * 256];
            const int f = cb + (tid + k * 256) * 4;  // %4==0, no row crossing
            const float yw  = (float)((f >> 9) + 1) * inv;
            const float xw0 = (float)((f & 511) + 1) * inv;
            const float e0 = __expf(v.x);
            const float e1 = __expf(v.y);
            const float e2 = __expf(v.z);
            const float e3 = __expf(v.w);
            const float es = e0 + e1 + e2 + e3;
            s  += es;
            sx += es * xw0 + inv * (e1 + 2.0f * e2 + 3.0f * e3);
            sy += es * yw;
        }

#pragma unroll
        for (int off = 32; off > 0; off >>= 1) {
            s  += __shfl_down(s,  off, 64);
            sx += __shfl_down(sx, off, 64);
            sy += __shfl_down(sy, off, 64);
        }
        if (lane == 0) { rs[wid] = s; rsx[wid] = sx; rsy[wid] = sy; }
        __syncthreads();
        if (tid == 0) {
            float fs = rs[0], fsx = rsx[0], fsy = rsy[0];
#pragma unroll
            for (int k = 1; k < 4; ++k) { fs += rs[k]; fsx += rsx[k]; fsy += rsy[k]; }
            wsf[cidx]              = fs;
            wsf[NPARTN + cidx]     = fsx;
            wsf[2 * NPARTN + cidx] = fsy;
        }
    } else {
        // ---- argmax partials from LDS: 4 independent chains ----
        float mvx = -1.0f, mvy = -1.0f, mvz = -1.0f, mvw = -1.0f;
        int   mix = 0, miy = 1, miz = 2, miw = 3;
#pragma unroll
        for (int k = 0; k < 8; ++k) {
            const float4 v = l4[tid + k * 256];
            const int f = cb + (tid + k * 256) * 4;
            if (v.x > mvx) { mvx = v.x; mix = f; }
            if (v.y > mvy) { mvy = v.y; miy = f + 1; }
            if (v.z > mvz) { mvz = v.z; miz = f + 2; }
            if (v.w > mvw) { mvw = v.w; miw = f + 3; }
        }
        float mv = mvx; int mi = mix;
        if (mvy > mv || (mvy == mv && miy < mi)) { mv = mvy; mi = miy; }
        if (mvz > mv || (mvz == mv && miz < mi)) { mv = mvz; mi = miz; }
        if (mvw > mv || (mvw == mv && miw < mi)) { mv = mvw; mi = miw; }

#pragma unroll
        for (int off = 32; off > 0; off >>= 1) {
            const float ov = __shfl_down(mv, off, 64);
            const int   oi = __shfl_down(mi, off, 64);
            if (ov > mv || (ov == mv && oi < mi)) { mv = ov; mi = oi; }
        }
        if (lane == 0) { rmv[wid] = mv; rmi[wid] = mi; }
        __syncthreads();
        if (tid == 0) {
            float fmv = rmv[0]; int fmi = rmi[0];
#pragma unroll
            for (int k = 1; k < 4; ++k)
                if (rmv[k] > fmv || (rmv[k] == fmv && rmi[k] < fmi)) { fmv = rmv[k]; fmi = rmi[k]; }
            wsf[3 * NPARTN + cidx] = fmv;
            wsi[cidx]              = fmi;
        }
    }
}

__global__ __launch_bounds__(128) void dsnt_finalize(
    const float* __restrict__ wsf, const int* __restrict__ wsi,
    float* __restrict__ out)
{
    __shared__ float px[BP], py[BP], tx[BP], ty[BP];
    __shared__ float wsum[2];
    const int tid = threadIdx.x; // 0..127, one pair per thread
    const int SPP = NPARTN / BP; // 32 partial records per pair

    {
        float s = 0.0f, sx = 0.0f, sy = 0.0f, mv = -1.0f;
        int mi = 0;
#pragma unroll
        for (int k = 0; k < SPP; ++k) {
            const int i = tid * SPP + k;   // ascending chunk order
            s  += wsf[i];
            sx += wsf[NPARTN + i];
            sy += wsf[2 * NPARTN + i];
            const float v = wsf[3 * NPARTN + i];
            const int  ii = wsi[i];
            if (v > mv || (v == mv && ii < mi)) { mv = v; mi = ii; }
        }
        px[tid] = sx / s;
        py[tid] = sy / s;
        tx[tid] = (float)((mi & 511) + 1) * (1.0f / 512.0f);
        ty[tid] = (float)((mi >> 9) + 1) * (1.0f / 512.0f);
    }
    __syncthreads();

    float term = 0.0f;
    if (tid < 64) {
        const int b = tid;
        const float px0 = px[2 * b], px1 = px[2 * b + 1];
        const float py0 = py[2 * b], py1 = py[2 * b + 1];
        const float tx0 = tx[2 * b], tx1 = tx[2 * b + 1];
        const float ty0 = ty[2 * b], ty1 = ty[2 * b + 1];

        const float ed0 = sqrtf((tx0 - px0) * (tx0 - px0) + (ty0 - py0) * (ty0 - py0));
        const float ed1 = sqrtf((tx1 - px1) * (tx1 - px1) + (ty1 - py1) * (ty1 - py1));

        const float pvx = px0 - px1, pvy = py0 - py1;
        const float tvx = tx0 - tx1, tvy = ty0 - ty1;
        const float pd = sqrtf(pvx * pvx + pvy * pvy);
        const float td = sqrtf(tvx * tvx + tvy * tvy);
        const float dot = pvx * tvx + pvy * tvy;
        const float cosd = 1.0f - cosf(dot / (pd * td));
        term = ed0 + ed1 + fabsf(pd - td) + cosd;
    }

#pragma unroll
    for (int off = 32; off > 0; off >>= 1)
        term += __shfl_down(term, off, 64);
    const int lane = tid & 63, wid = tid >> 6;
    if (lane == 0) wsum[wid] = term;
    __syncthreads();
    if (tid == 0) out[0] = (wsum[0] + wsum[1]) * (1.0f / 64.0f);
}

extern "C" void kernel_launch(void* const* d_in, const int* in_sizes, int n_in,
                              void* d_out, int out_size, void* d_ws, size_t ws_size,
                              hipStream_t stream)
{
    const float* inp = (const float*)d_in[0];
    const float* tgt = (const float*)d_in[1];
    float* out = (float*)d_out;
    float* wsf = (float*)d_ws;
    int*   wsi = (int*)((float*)d_ws + 4 * NPARTN);

    dsnt_partial<<<2 * NBLK, 256, 0, stream>>>(inp, tgt, wsf, wsi);
    dsnt_finalize<<<1, 128, 0, stream>>>(wsf, wsi, out);
}